// Round 5
// baseline (1202.466 us; speedup 1.0000x reference)
//
#include <hip/hip_runtime.h>
#include <hip/hip_bf16.h>

typedef __hip_bfloat16 bf16;

#define BB 4
#define NN 2048
#define DD 128
#define KK 32
#define MD 16
#define H1 530
#define NC 1060
#define NROWS (BB*NN)
#define NB 2048   // rows per batch

__device__ __forceinline__ float bf2f(bf16 x) { return __bfloat162float(x); }
__device__ __forceinline__ float silu_f(float x) { return __fdividef(x, 1.0f + __expf(-x)); }

// ---------------------------------------------------------------- mean kernel
__global__ __launch_bounds__(256) void mean_kernel(const float* __restrict__ coors,
                                                   float* __restrict__ ws_mean) {
    int b = blockIdx.x, tid = threadIdx.x;
    float sx = 0.f, sy = 0.f, sz = 0.f;
    const float* cb = coors + (size_t)b * NN * 3;
    for (int i = tid; i < NN; i += 256) {
        sx += cb[i*3+0];
        sy += cb[i*3+1];
        sz += cb[i*3+2];
    }
    __shared__ float sm[3][256];
    sm[0][tid] = sx; sm[1][tid] = sy; sm[2][tid] = sz;
    __syncthreads();
    for (int off = 128; off > 0; off >>= 1) {
        if (tid < off) {
            sm[0][tid] += sm[0][tid+off];
            sm[1][tid] += sm[1][tid+off];
            sm[2][tid] += sm[2][tid+off];
        }
        __syncthreads();
    }
    if (tid == 0) {
        ws_mean[b*3+0] = sm[0][0] * (1.f/NN);
        ws_mean[b*3+1] = sm[1][0] * (1.f/NN);
        ws_mean[b*3+2] = sm[2][0] * (1.f/NN);
    }
}

// ---------------------------------------------------------------- topk kernel
// one wave per row i: 64 lanes x 32 candidates; 32 extraction rounds via
// (hi,lo) 32-bit pair butterfly argmin (unique key, smallest-j tiebreak).
__global__ __launch_bounds__(256) void topk_kernel(const float* __restrict__ coors,
                                                   int* __restrict__ ws_idx,
                                                   float* __restrict__ ws_dist) {
    __shared__ float cx[NN], cy[NN], cz[NN];
    int b = blockIdx.x >> 9;          // 512 blocks per batch
    int grp = blockIdx.x & 511;
    const float* cb = coors + (size_t)b * NN * 3;
    for (int n = threadIdx.x; n < NN; n += 256) {
        cx[n] = cb[n*3+0];
        cy[n] = cb[n*3+1];
        cz[n] = cb[n*3+2];
    }
    __syncthreads();
    int lane = threadIdx.x & 63, wid = threadIdx.x >> 6;
    int i = grp*4 + wid;
    float ix = cx[i], iy = cy[i], iz = cz[i];
    unsigned keys[32];
#pragma unroll
    for (int s = 0; s < 32; ++s) {
        int j = s*64 + lane;
        float dx = ix - cx[j], dy = iy - cy[j], dz = iz - cz[j];
        float d = dx*dx + dy*dy + dz*dz;
        keys[s] = __float_as_uint(d);   // d >= 0 -> order-preserving
    }
    int r = (b << 11) | i;
    int* oi = ws_idx + (size_t)r * KK;
    float* od = ws_dist + (size_t)r * KK;
    for (int t = 0; t < KK; ++t) {
        unsigned bbv = 0xFFFFFFFFu; int bs = 0;
#pragma unroll
        for (int s = 0; s < 32; ++s) if (keys[s] < bbv) { bbv = keys[s]; bs = s; }
        unsigned hi = bbv;
        unsigned lo = (unsigned)(bs*64 + lane);
#pragma unroll
        for (int mm = 1; mm < 64; mm <<= 1) {
            unsigned ohi = __shfl_xor(hi, mm, 64);
            unsigned olo = __shfl_xor(lo, mm, 64);
            if (ohi < hi || (ohi == hi && olo < lo)) { hi = ohi; lo = olo; }
        }
        unsigned jw = lo;
        if (lane == 0) {
            oi[t] = (int)jw;
            od[t] = __uint_as_float(hi);
        }
        int slot = (int)(jw >> 6);
        bool win = ((jw & 63u) == (unsigned)lane);
#pragma unroll
        for (int s = 0; s < 32; ++s) keys[s] = (win && s == slot) ? 0xFFFFFFFFu : keys[s];
    }
}

// ---------------------------------------------------------------- AC GEMM (f32 tiled)
struct GemmSmem {
    float At[64][65];   // [row][k], +1 pad -> conflict-free scalar reads
    float Bt[64][64];   // [k][col], float4 reads
};

__device__ __forceinline__ void gemm_compute(GemmSmem* s, int tr, int tc, float acc[4][4]) {
#pragma unroll
    for (int kk = 0; kk < 64; ++kk) {
        float a0 = s->At[4*tr+0][kk];
        float a1 = s->At[4*tr+1][kk];
        float a2 = s->At[4*tr+2][kk];
        float a3 = s->At[4*tr+3][kk];
        float4 b4 = *reinterpret_cast<const float4*>(&s->Bt[kk][4*tc]);
        acc[0][0] += a0*b4.x; acc[0][1] += a0*b4.y; acc[0][2] += a0*b4.z; acc[0][3] += a0*b4.w;
        acc[1][0] += a1*b4.x; acc[1][1] += a1*b4.y; acc[1][2] += a1*b4.z; acc[1][3] += a1*b4.w;
        acc[2][0] += a2*b4.x; acc[2][1] += a2*b4.y; acc[2][2] += a2*b4.z; acc[2][3] += a2*b4.w;
        acc[3][0] += a3*b4.x; acc[3][1] += a3*b4.y; acc[3][2] += a3*b4.z; acc[3][3] += a3*b4.w;
    }
}

// AC_b = feats_b(2048x128) @ [W1_top | W1_bot](128x1060), stored bf16 (internal)
__global__ __launch_bounds__(256) void gemm_ac_kernel(const float* __restrict__ feats_b,
                                                      const float* __restrict__ edge_w1,
                                                      bf16* __restrict__ AC) {
    __shared__ GemmSmem s;
    int tid = threadIdx.x;
    int tc = tid & 15, tr = tid >> 4;
    int c0 = blockIdx.x * 64, r0 = blockIdx.y * 64;
    float acc[4][4] = {};
    for (int k0 = 0; k0 < 128; k0 += 64) {
#pragma unroll
        for (int it = 0; it < 16; ++it) {
            int e = it*256 + tid;
            int kk = e & 63, rr = e >> 6;
            s.At[rr][kk] = feats_b[(size_t)(r0+rr)*DD + k0 + kk];
        }
#pragma unroll
        for (int it = 0; it < 16; ++it) {
            int e = it*256 + tid;
            int cc = e & 63, kk = e >> 6;
            int cg = c0 + cc, kg = k0 + kk;
            float v;
            if (cg < H1)       v = edge_w1[(size_t)kg*H1 + cg];
            else if (cg < NC)  v = edge_w1[(size_t)(128+kg)*H1 + (cg - H1)];
            else               v = 0.f;
            s.Bt[kk][cc] = v;
        }
        __syncthreads();
        gemm_compute(&s, tr, tc, acc);
        __syncthreads();
    }
#pragma unroll
    for (int q = 0; q < 4; ++q) {
        int row = r0 + 4*tr + q;
#pragma unroll
        for (int u = 0; u < 4; ++u) {
            int col = c0 + 4*tc + u;
            if (col < NC) AC[(size_t)row*NC + col] = __float2bfloat16(acc[q][u]);
        }
    }
}

// ---------------------------------------------------------------- edge kernel (per batch)
// one wave per node-row; edges in groups of 4; 530-dim hidden distributed
// lane+64s; m-partials v[e*16+c] butterfly-transpose-reduced so lane l holds
// m_pre for (e=l>>4, c=l&15).
__global__ __launch_bounds__(256) void edge_kernel(
    int b,
    const float* __restrict__ coors, const bf16* __restrict__ AC,
    const int* __restrict__ ws_idx, const float* __restrict__ ws_dist,
    const float* __restrict__ ws_mean,
    const float* __restrict__ edge_w1, const float* __restrict__ edge_b1,
    const float* __restrict__ edge_w2, const float* __restrict__ edge_b2,
    const float* __restrict__ coor_w1, const float* __restrict__ coor_b1,
    const float* __restrict__ coor_w2, const float* __restrict__ coor_b2,
    const float* __restrict__ cross_w1, const float* __restrict__ cross_b1,
    const float* __restrict__ cross_w2, const float* __restrict__ cross_b2,
    float* __restrict__ ws_mi, float* __restrict__ out_coors) {

    __shared__ unsigned w2Lu[H1*9];   // packed bf16 pairs, pitch 9 u32 (odd -> conflict-free)
    __shared__ float WencL[9*H1];
    __shared__ float cw1L[16*64], xw1L[16*64];
    __shared__ float cw2L[64], xw2L[64], b1cL[64], b1xL[64], b2L[16];

    int tid = threadIdx.x;
    for (int e = tid; e < H1*8; e += 256) {
        int h = e >> 3, cp = e & 7;
        unsigned lo = (unsigned)__bfloat16_as_ushort(__float2bfloat16(edge_w2[2*e]));
        unsigned hi = (unsigned)__bfloat16_as_ushort(__float2bfloat16(edge_w2[2*e+1]));
        w2Lu[h*9 + cp] = lo | (hi << 16);
    }
    for (int e = tid; e < 9*H1; e += 256) WencL[e] = edge_w1[(size_t)256*H1 + e];
    for (int e = tid; e < 1024; e += 256) { cw1L[e] = coor_w1[e]; xw1L[e] = cross_w1[e]; }
    if (tid < 64) {
        cw2L[tid] = coor_w2[tid]; xw2L[tid] = cross_w2[tid];
        b1cL[tid] = coor_b1[tid]; b1xL[tid] = cross_b1[tid];
    }
    if (tid < 16) b2L[tid] = edge_b2[tid];
    __syncthreads();

    int lane = tid & 63, wid = tid >> 6;
    int r_local = blockIdx.x*4 + wid;      // batch-local row
    int r = (b << 11) | r_local;           // global row
    const float b2c = coor_b2[0];
    const float b2x = cross_b2[0];

    float a[9];
#pragma unroll
    for (int s = 0; s < 9; ++s) {
        int h = lane + 64*s;
        a[s] = (h < H1) ? (bf2f(AC[(size_t)r_local*NC + h]) + edge_b1[h]) : 0.f;
    }
    float mx = ws_mean[b*3+0], my = ws_mean[b*3+1], mz = ws_mean[b*3+2];
    float cix = coors[(size_t)r*3+0];
    float ciy = coors[(size_t)r*3+1];
    float ciz = coors[(size_t)r*3+2];
    float cmix = cix - mx, cmiy = ciy - my, cmiz = ciz - mz;

    const int c_l = lane & 15, e_l = lane >> 4;
    float macc = 0.f, caccx = 0.f, caccy = 0.f, caccz = 0.f;
    const int* idxr = ws_idx + (size_t)r * KK;
    const float* distr = ws_dist + (size_t)r * KK;

    for (int g = 0; g < 8; ++g) {
        int js[4]; float dsv[4];
#pragma unroll
        for (int e = 0; e < 4; ++e) { js[e] = idxr[g*4+e]; dsv[e] = distr[g*4+e]; }

        float hb[4][9];
#pragma unroll
        for (int e = 0; e < 4; ++e) {
            float d = dsv[e];
            float e0 = __sinf(d),        e1 = __sinf(d*0.5f);
            float e2 = __sinf(d*0.25f),  e3 = __sinf(d*0.125f);
            float e4 = __cosf(d),        e5 = __cosf(d*0.5f);
            float e6 = __cosf(d*0.25f),  e7 = __cosf(d*0.125f);
            const bf16* Crow = AC + (size_t)js[e]*NC + H1;
#pragma unroll
            for (int s = 0; s < 9; ++s) {
                int h = lane + 64*s;
                if (h < H1) {
                    float x = a[s] + bf2f(Crow[h]);
                    x += e0*WencL[h]        + e1*WencL[H1+h]   + e2*WencL[2*H1+h]
                       + e3*WencL[3*H1+h]   + e4*WencL[4*H1+h] + e5*WencL[5*H1+h]
                       + e6*WencL[6*H1+h]   + e7*WencL[7*H1+h] + d *WencL[8*H1+h];
                    hb[e][s] = silu_f(x);
                } else hb[e][s] = 0.f;
            }
        }

        float v[64];
#pragma unroll
        for (int q = 0; q < 64; ++q) v[q] = 0.f;
#pragma unroll
        for (int s = 0; s < 9; ++s) {
            int h = lane + 64*s; if (h > H1-1) h = H1-1;   // hb==0 there
            const unsigned* wrow = &w2Lu[h*9];
#pragma unroll
            for (int cp = 0; cp < 8; ++cp) {
                unsigned wp = wrow[cp];
                float wfx = __uint_as_float(wp << 16);          // bf16 -> f32: bits<<16
                float wfy = __uint_as_float(wp & 0xFFFF0000u);
#pragma unroll
                for (int e = 0; e < 4; ++e) {
                    v[e*16 + 2*cp    ] += hb[e][s]*wfx;
                    v[e*16 + 2*cp + 1] += hb[e][s]*wfy;
                }
            }
        }
        // butterfly transpose-reduce: lane l ends with sum over lanes of v[l]
#pragma unroll
        for (int bit = 0; bit < 6; ++bit) {
            int mybit = (lane >> bit) & 1;
#pragma unroll
            for (int t2 = 0; t2 < (32 >> bit); ++t2) {
                float a0v = v[2*t2], a1v = v[2*t2+1];
                float keep = mybit ? a1v : a0v;
                float send = mybit ? a0v : a1v;
                float recv = __shfl_xor(send, 1 << bit, 64);
                v[t2] = keep + recv;
            }
        }
        float m = silu_f(v[0] + b2L[c_l]);   // m_ij for (edge e_l, channel c_l)
        macc += m;

        // coor / cross heads: 16 -> 64 -> 1
        float hc0 = b1cL[c_l], hc1 = b1cL[c_l+16], hc2 = b1cL[c_l+32], hc3 = b1cL[c_l+48];
        float hx0 = b1xL[c_l], hx1 = b1xL[c_l+16], hx2 = b1xL[c_l+32], hx3 = b1xL[c_l+48];
#pragma unroll
        for (int cc = 0; cc < 16; ++cc) {
            float mm = __shfl(m, (lane & 48) | cc, 64);
            hc0 += mm*cw1L[cc*64 + c_l];
            hc1 += mm*cw1L[cc*64 + c_l+16];
            hc2 += mm*cw1L[cc*64 + c_l+32];
            hc3 += mm*cw1L[cc*64 + c_l+48];
            hx0 += mm*xw1L[cc*64 + c_l];
            hx1 += mm*xw1L[cc*64 + c_l+16];
            hx2 += mm*xw1L[cc*64 + c_l+32];
            hx3 += mm*xw1L[cc*64 + c_l+48];
        }
        float pc = silu_f(hc0)*cw2L[c_l] + silu_f(hc1)*cw2L[c_l+16]
                 + silu_f(hc2)*cw2L[c_l+32] + silu_f(hc3)*cw2L[c_l+48];
        float px = silu_f(hx0)*xw2L[c_l] + silu_f(hx1)*xw2L[c_l+16]
                 + silu_f(hx2)*xw2L[c_l+32] + silu_f(hx3)*xw2L[c_l+48];
        pc += __shfl_xor(pc, 1, 64); pc += __shfl_xor(pc, 2, 64);
        pc += __shfl_xor(pc, 4, 64); pc += __shfl_xor(pc, 8, 64);
        px += __shfl_xor(px, 1, 64); px += __shfl_xor(px, 2, 64);
        px += __shfl_xor(px, 4, 64); px += __shfl_xor(px, 8, 64);
        float cwv = pc + b2c;
        float ccwv = px + b2x;

        int j = (e_l == 0) ? js[0] : ((e_l == 1) ? js[1] : ((e_l == 2) ? js[2] : js[3]));
        size_t jb = (size_t)((b<<11) | j) * 3;
        float cjx = coors[jb], cjy = coors[jb+1], cjz = coors[jb+2];
        float relx = cix - cjx, rely = ciy - cjy, relz = ciz - cjz;
        float cmjx = cjx - mx, cmjy = cjy - my, cmjz = cjz - mz;
        float crx = cmiy*cmjz - cmiz*cmjy;
        float cry = cmiz*cmjx - cmix*cmjz;
        float crz = cmix*cmjy - cmiy*cmjx;
        caccx += cwv*relx + ccwv*crx;
        caccy += cwv*rely + ccwv*cry;
        caccz += cwv*relz + ccwv*crz;
    }

    macc += __shfl_xor(macc, 16, 64); macc += __shfl_xor(macc, 32, 64);
    if (lane < 16) ws_mi[(size_t)r*MD + lane] = macc;

    caccx += __shfl_xor(caccx, 16, 64); caccx += __shfl_xor(caccx, 32, 64);
    caccy += __shfl_xor(caccy, 16, 64); caccy += __shfl_xor(caccy, 32, 64);
    caccz += __shfl_xor(caccz, 16, 64); caccz += __shfl_xor(caccz, 32, 64);
    if (lane == 0) {
        out_coors[(size_t)r*3+0] = cix + caccx;
        out_coors[(size_t)r*3+1] = ciy + caccy;
        out_coors[(size_t)r*3+2] = ciz + caccz;
    }
}

// ---------------------------------------------------------------- node MLP (simple, f32)
// hidden[row,col] = silu(sum_k [feats|mi][row,k] * w1[k,col] + b1[col]); block=row
__global__ __launch_bounds__(256) void node1_kernel(const float* __restrict__ feats,
                                                    const float* __restrict__ mi,
                                                    const float* __restrict__ w1,
                                                    const float* __restrict__ b1,
                                                    float* __restrict__ hidden) {
    int row = blockIdx.x;
    int col = threadIdx.x;
    float acc = b1[col];
    for (int k = 0; k < 128; ++k)
        acc += feats[(size_t)row*DD + k] * w1[(size_t)k*256 + col];
    for (int k = 0; k < 16; ++k)
        acc += mi[(size_t)row*MD + k] * w1[(size_t)(128+k)*256 + col];
    hidden[(size_t)row*256 + col] = silu_f(acc);
}

// out[row,col] = sum_k hidden[row,k]*w2[k,col] + b2[col] + feats[row,col]; block=row
__global__ __launch_bounds__(128) void node2_kernel(const float* __restrict__ hidden,
                                                    const float* __restrict__ w2,
                                                    const float* __restrict__ b2,
                                                    const float* __restrict__ feats,
                                                    float* __restrict__ out_node) {
    int row = blockIdx.x;
    int col = threadIdx.x;
    float acc = b2[col];
    for (int k = 0; k < 256; ++k)
        acc += hidden[(size_t)row*256 + k] * w2[(size_t)k*DD + col];
    out_node[(size_t)row*DD + col] = acc + feats[(size_t)row*DD + col];
}

// ---------------------------------------------------------------- launch
// ws layout (total ~15.2 MB):
//   [0,64)            ws_mean (12 floats)
//   [64, +1MB)        ws_idx  (8192*32 int)
//   [1048640, +1MB)   ws_dist (8192*32 float)
//   [2097216, +512K)  ws_mi   (8192*16 float)
//   [2621504, +4.34MB) AC (per-batch 2048*1060 bf16)
//   [6965568, +8MB)   hidden (8192*256 f32)
extern "C" void kernel_launch(void* const* d_in, const int* in_sizes, int n_in,
                              void* d_out, int out_size, void* d_ws, size_t ws_size,
                              hipStream_t stream) {
    const float* feats    = (const float*)d_in[0];
    const float* coors    = (const float*)d_in[1];
    const float* edge_w1  = (const float*)d_in[2];
    const float* edge_b1  = (const float*)d_in[3];
    const float* edge_w2  = (const float*)d_in[4];
    const float* edge_b2  = (const float*)d_in[5];
    const float* coor_w1  = (const float*)d_in[6];
    const float* coor_b1  = (const float*)d_in[7];
    const float* coor_w2  = (const float*)d_in[8];
    const float* coor_b2  = (const float*)d_in[9];
    const float* cross_w1 = (const float*)d_in[10];
    const float* cross_b1 = (const float*)d_in[11];
    const float* cross_w2 = (const float*)d_in[12];
    const float* cross_b2 = (const float*)d_in[13];
    const float* node_w1  = (const float*)d_in[14];
    const float* node_b1  = (const float*)d_in[15];
    const float* node_w2  = (const float*)d_in[16];
    const float* node_b2  = (const float*)d_in[17];

    char* ws = (char*)d_ws;
    float* ws_mean = (float*)ws;
    int*   ws_idx  = (int*)(ws + 64);
    float* ws_dist = (float*)(ws + 1048640);
    float* ws_mi   = (float*)(ws + 2097216);
    bf16*  AC      = (bf16*)(ws + 2621504);
    float* hidden  = (float*)(ws + 6965568);

    float* out_node  = (float*)d_out;
    float* out_coors = out_node + (size_t)NROWS * DD;

    mean_kernel<<<BB, 256, 0, stream>>>(coors, ws_mean);
    topk_kernel<<<NROWS/4, 256, 0, stream>>>(coors, ws_idx, ws_dist);
    for (int b = 0; b < BB; ++b) {
        gemm_ac_kernel<<<dim3(17, NB/64), 256, 0, stream>>>(feats + (size_t)b*NB*DD, edge_w1, AC);
        edge_kernel<<<NB/4, 256, 0, stream>>>(b, coors, AC, ws_idx, ws_dist, ws_mean,
                                              edge_w1, edge_b1, edge_w2, edge_b2,
                                              coor_w1, coor_b1, coor_w2, coor_b2,
                                              cross_w1, cross_b1, cross_w2, cross_b2,
                                              ws_mi, out_coors);
    }
    node1_kernel<<<NROWS, 256, 0, stream>>>(feats, ws_mi, node_w1, node_b1, hidden);
    node2_kernel<<<NROWS, 128, 0, stream>>>(hidden, node_w2, node_b2, feats, out_node);
}

// Round 6
// 658.142 us; speedup vs baseline: 1.8271x; 1.8271x over previous
//
#include <hip/hip_runtime.h>
#include <hip/hip_bf16.h>

typedef __hip_bfloat16 bf16;
typedef __attribute__((ext_vector_type(8)))  short s8v;   // 8 bf16 (4 VGPRs)
typedef __attribute__((ext_vector_type(4)))  float f4v;
typedef __attribute__((ext_vector_type(16))) float f16v;

#define BB 4
#define NN 2048
#define DD 128
#define KK 32
#define MD 16
#define H1 530
#define HP 544            // padded hidden dim
#define WROW 1088         // ACall row: [ACa 544 | ACc 544]
#define NROWS (BB*NN)
#define RCHUNK 4096       // rows per 2-batch chunk

__device__ __forceinline__ float silu_f(float x) { return __fdividef(x, 1.0f + __expf(-x)); }
__device__ __forceinline__ float blo(unsigned u) { return __uint_as_float(u << 16); }
__device__ __forceinline__ float bhi(unsigned u) { return __uint_as_float(u & 0xffff0000u); }
__device__ __forceinline__ short f2bs(float x) { return (short)__bfloat16_as_ushort(__float2bfloat16(x)); }

// ---------------------------------------------------------------- mean kernel
__global__ __launch_bounds__(256) void mean_kernel(const float* __restrict__ coors,
                                                   float* __restrict__ ws_mean) {
    int b = blockIdx.x, tid = threadIdx.x;
    float sx = 0.f, sy = 0.f, sz = 0.f;
    const float* cb = coors + (size_t)b * NN * 3;
    for (int i = tid; i < NN; i += 256) {
        sx += cb[i*3+0]; sy += cb[i*3+1]; sz += cb[i*3+2];
    }
    __shared__ float sm[3][256];
    sm[0][tid] = sx; sm[1][tid] = sy; sm[2][tid] = sz;
    __syncthreads();
    for (int off = 128; off > 0; off >>= 1) {
        if (tid < off) {
            sm[0][tid] += sm[0][tid+off];
            sm[1][tid] += sm[1][tid+off];
            sm[2][tid] += sm[2][tid+off];
        }
        __syncthreads();
    }
    if (tid == 0) {
        ws_mean[b*3+0] = sm[0][0] * (1.f/NN);
        ws_mean[b*3+1] = sm[1][0] * (1.f/NN);
        ws_mean[b*3+2] = sm[2][0] * (1.f/NN);
    }
}

// ---------------------------------------------------------------- topk kernel
__global__ __launch_bounds__(256) void topk_kernel(const float* __restrict__ coors,
                                                   int* __restrict__ ws_idx,
                                                   float* __restrict__ ws_dist) {
    __shared__ float cx[NN], cy[NN], cz[NN];
    int b = blockIdx.x >> 9;
    int grp = blockIdx.x & 511;
    const float* cb = coors + (size_t)b * NN * 3;
    for (int n = threadIdx.x; n < NN; n += 256) {
        cx[n] = cb[n*3+0]; cy[n] = cb[n*3+1]; cz[n] = cb[n*3+2];
    }
    __syncthreads();
    int lane = threadIdx.x & 63, wid = threadIdx.x >> 6;
    int i = grp*4 + wid;
    float ix = cx[i], iy = cy[i], iz = cz[i];
    unsigned keys[32];
#pragma unroll
    for (int s = 0; s < 32; ++s) {
        int j = s*64 + lane;
        float dx = ix - cx[j], dy = iy - cy[j], dz = iz - cz[j];
        float d = dx*dx + dy*dy + dz*dz;
        keys[s] = __float_as_uint(d);
    }
    int r = (b << 11) | i;
    int* oi = ws_idx + (size_t)r * KK;
    float* od = ws_dist + (size_t)r * KK;
    for (int t = 0; t < KK; ++t) {
        unsigned bbv = 0xFFFFFFFFu; int bs = 0;
#pragma unroll
        for (int s = 0; s < 32; ++s) if (keys[s] < bbv) { bbv = keys[s]; bs = s; }
        unsigned hi = bbv;
        unsigned lo = (unsigned)(bs*64 + lane);
#pragma unroll
        for (int mm = 1; mm < 64; mm <<= 1) {
            unsigned ohi = __shfl_xor(hi, mm, 64);
            unsigned olo = __shfl_xor(lo, mm, 64);
            if (ohi < hi || (ohi == hi && olo < lo)) { hi = ohi; lo = olo; }
        }
        unsigned jw = lo;
        if (lane == 0) { oi[t] = (int)jw; od[t] = __uint_as_float(hi); }
        int slot = (int)(jw >> 6);
        bool win = ((jw & 63u) == (unsigned)lane);
#pragma unroll
        for (int s = 0; s < 32; ++s) keys[s] = (win && s == slot) ? 0xFFFFFFFFu : keys[s];
    }
}

// ---------------------------------------------------------------- AC GEMM (f32 tiled)
// ACall[row][0..543]   = feats_row @ W1_top (+ b1), 544-padded
// ACall[row][544..1087]= feats_row @ W1_bot,        544-padded
struct GemmSmem {
    float At[64][65];
    float Bt[64][64];
};

__device__ __forceinline__ void gemm_compute(GemmSmem* s, int tr, int tc, float acc[4][4]) {
#pragma unroll
    for (int kk = 0; kk < 64; ++kk) {
        float a0 = s->At[4*tr+0][kk];
        float a1 = s->At[4*tr+1][kk];
        float a2 = s->At[4*tr+2][kk];
        float a3 = s->At[4*tr+3][kk];
        float4 b4 = *reinterpret_cast<const float4*>(&s->Bt[kk][4*tc]);
        acc[0][0] += a0*b4.x; acc[0][1] += a0*b4.y; acc[0][2] += a0*b4.z; acc[0][3] += a0*b4.w;
        acc[1][0] += a1*b4.x; acc[1][1] += a1*b4.y; acc[1][2] += a1*b4.z; acc[1][3] += a1*b4.w;
        acc[2][0] += a2*b4.x; acc[2][1] += a2*b4.y; acc[2][2] += a2*b4.z; acc[2][3] += a2*b4.w;
        acc[3][0] += a3*b4.x; acc[3][1] += a3*b4.y; acc[3][2] += a3*b4.z; acc[3][3] += a3*b4.w;
    }
}

__global__ __launch_bounds__(256) void gemm_ac_kernel(const float* __restrict__ feats_c,
                                                      const float* __restrict__ ew1,
                                                      const float* __restrict__ eb1,
                                                      bf16* __restrict__ ACall) {
    __shared__ GemmSmem s;
    int tid = threadIdx.x;
    int tc = tid & 15, tr = tid >> 4;
    int c0 = blockIdx.x * 64, r0 = blockIdx.y * 64;
    float acc[4][4] = {};
    for (int k0 = 0; k0 < 128; k0 += 64) {
#pragma unroll
        for (int it = 0; it < 16; ++it) {
            int e = it*256 + tid;
            int kk = e & 63, rr = e >> 6;
            s.At[rr][kk] = feats_c[(size_t)(r0+rr)*DD + k0 + kk];
        }
#pragma unroll
        for (int it = 0; it < 16; ++it) {
            int e = it*256 + tid;
            int cc = e & 63, kk = e >> 6;
            int cg = c0 + cc, kg = k0 + kk;
            float v = 0.f;
            if (cg < HP) { if (cg < H1) v = ew1[(size_t)kg*H1 + cg]; }
            else { int h = cg - HP; if (h < H1) v = ew1[(size_t)(128+kg)*H1 + h]; }
            s.Bt[kk][cc] = v;
        }
        __syncthreads();
        gemm_compute(&s, tr, tc, acc);
        __syncthreads();
    }
#pragma unroll
    for (int q = 0; q < 4; ++q) {
        int row = r0 + 4*tr + q;
#pragma unroll
        for (int u = 0; u < 4; ++u) {
            int cg = c0 + 4*tc + u;
            float bias = (cg < H1) ? eb1[cg] : 0.f;
            ACall[(size_t)row*WROW + cg] = __float2bfloat16(acc[q][u] + bias);
        }
    }
}

// ---------------------------------------------------------------- edge kernel (MFMA)
// 4 waves/block, 1 node-row per wave; 2 halves of 16 edges; hidden computed
// directly in MFMA A-layout (lane: edge=l&15, k=kc*32+(l>>4)*8+j), W2 pre-
// packed in B-frag order in LDS; heads via 32x32x16 MFMA on m roundtripped
// through LDS (B = mL^T, free transpose).
__global__ __launch_bounds__(256, 3) void edge_kernel(
    int chunk,
    const float* __restrict__ coors, const bf16* __restrict__ ACall,
    const int* __restrict__ ws_idx, const float* __restrict__ ws_dist,
    const float* __restrict__ ws_mean,
    const float* __restrict__ edge_w1, const float* __restrict__ edge_w2,
    const float* __restrict__ edge_b2,
    const float* __restrict__ coor_w1, const float* __restrict__ coor_b1,
    const float* __restrict__ coor_w2, const float* __restrict__ coor_b2,
    const float* __restrict__ cross_w1, const float* __restrict__ cross_b1,
    const float* __restrict__ cross_w2, const float* __restrict__ cross_b2,
    float* __restrict__ ws_mi, float* __restrict__ out_coors) {

    __shared__ s8v  w2F[1088];                 // W2 B-frags, [kc][lane]      17408 B
    __shared__ uint4 WencP[612];               // Wenc bf16-packed [t][68]     9792 B
    __shared__ uint4 aL[4][68];                // per-wave ACa row (544 bf16)  4352 B
    __shared__ __align__(16) short mL[4][32][16]; // per-wave m (bf16)         4096 B
    __shared__ float encL[4][32][12];          // per-wave enc + j             6144 B
    __shared__ float b1cL[64], b1xL[64], cw2L[64], xw2L[64], b2L[16];

    int tid = threadIdx.x, l = tid & 63, wid = tid >> 6;

    // ---- stage W2 B-frags: lane ln of frag kc holds W2[kc*32+(ln>>4)*8+j][ln&15]
    for (int s = tid; s < 1088; s += 256) {
        int kc = s >> 6, ln = s & 63;
        int kb = kc*32 + ((ln >> 4) * 8), c = ln & 15;
        s8v t;
#pragma unroll
        for (int j = 0; j < 8; ++j) {
            int k = kb + j;
            float v = (k < H1) ? edge_w2[(size_t)k*MD + c] : 0.f;
            t[j] = f2bs(v);
        }
        w2F[s] = t;
    }
    // ---- stage Wenc rows (edge_w1 rows 256..264) as packed bf16
    for (int s = tid; s < 612; s += 256) {
        int tt = s / 68, q = s % 68;
        uint4 u;
        unsigned* pu = (unsigned*)&u;
#pragma unroll
        for (int p = 0; p < 4; ++p) {
            int k0 = q*8 + p*2;
            float v0 = (k0   < H1) ? edge_w1[(size_t)(256+tt)*H1 + k0]   : 0.f;
            float v1 = (k0+1 < H1) ? edge_w1[(size_t)(256+tt)*H1 + k0+1] : 0.f;
            pu[p] = (unsigned)(unsigned short)__bfloat16_as_ushort(__float2bfloat16(v0))
                  | ((unsigned)(unsigned short)__bfloat16_as_ushort(__float2bfloat16(v1)) << 16);
        }
        WencP[s] = u;
    }
    if (tid < 64) {
        b1cL[tid] = coor_b1[tid]; b1xL[tid] = cross_b1[tid];
        cw2L[tid] = coor_w2[tid]; xw2L[tid] = cross_w2[tid];
    }
    if (tid < 16) b2L[tid] = edge_b2[tid];
    __syncthreads();

    // ---- cw1/xw1 A-frags (32x32x16): lane: m=h=(l&31)+32*tile, k=ch=(l>>5)*8+j
    s8v cA0, cA1, xA0, xA1;
    {
        int hb = l & 31, ks = (l >> 5) * 8;
#pragma unroll
        for (int j = 0; j < 8; ++j) {
            int ch = ks + j;
            cA0[j] = f2bs(coor_w1[(size_t)ch*64 + hb]);
            cA1[j] = f2bs(coor_w1[(size_t)ch*64 + hb + 32]);
            xA0[j] = f2bs(cross_w1[(size_t)ch*64 + hb]);
            xA1[j] = f2bs(cross_w1[(size_t)ch*64 + hb + 32]);
        }
    }

    int r_local = blockIdx.x*4 + wid;             // 0..4095 within chunk
    int b = chunk*2 + (r_local >> 11);
    int r = (b << 11) | (r_local & 2047);

    // stage own ACa row (a + b1, 544 bf16 = 68 uint4)
    const uint4* rowA4 = (const uint4*)(ACall + (size_t)r_local * WROW);
    aL[wid][l] = rowA4[l < 68 ? l : 0];
    if (l < 4) aL[wid][l + 64] = rowA4[l + 64];

    float mx = ws_mean[b*3+0], my = ws_mean[b*3+1], mz = ws_mean[b*3+2];
    float cix = coors[(size_t)r*3+0], ciy = coors[(size_t)r*3+1], ciz = coors[(size_t)r*3+2];
    float cmix = cix-mx, cmiy = ciy-my, cmiz = ciz-mz;

    const int* idxr = ws_idx + (size_t)r * KK;
    const float* distr = ws_dist + (size_t)r * KK;
    if (l < 32) {
        float d = distr[l];
        encL[wid][l][0] = __sinf(d);
        encL[wid][l][1] = __sinf(d*0.5f);
        encL[wid][l][2] = __sinf(d*0.25f);
        encL[wid][l][3] = __sinf(d*0.125f);
        encL[wid][l][4] = __cosf(d);
        encL[wid][l][5] = __cosf(d*0.5f);
        encL[wid][l][6] = __cosf(d*0.25f);
        encL[wid][l][7] = __cosf(d*0.125f);
        encL[wid][l][8] = d;
        encL[wid][l][9] = __int_as_float(idxr[l]);
    }
    // (same-wave LDS produce/consume: compiler inserts lgkmcnt waits; no barrier)

    float macc = 0.f;
    const int qi = l >> 4;

#pragma unroll 1
    for (int hf = 0; hf < 2; ++hf) {
        int e = hf*16 + (l & 15);
        float en[9];
#pragma unroll
        for (int t = 0; t < 9; ++t) en[t] = encL[wid][e][t];
        int j = __float_as_int(encL[wid][e][9]);
        int jrow = ((r_local >> 11) << 11) | j;
        const uint4* cPtr = (const uint4*)(ACall + (size_t)jrow*WROW + HP);

        f4v acc = {0.f, 0.f, 0.f, 0.f};
#pragma unroll 1
        for (int kc = 0; kc < 17; ++kc) {
            int idx4 = kc*4 + qi;
            uint4 aA = aL[wid][idx4];
            uint4 cC = cPtr[idx4];
            float x[8];
            x[0]=blo(aA.x)+blo(cC.x); x[1]=bhi(aA.x)+bhi(cC.x);
            x[2]=blo(aA.y)+blo(cC.y); x[3]=bhi(aA.y)+bhi(cC.y);
            x[4]=blo(aA.z)+blo(cC.z); x[5]=bhi(aA.z)+bhi(cC.z);
            x[6]=blo(aA.w)+blo(cC.w); x[7]=bhi(aA.w)+bhi(cC.w);
#pragma unroll
            for (int t = 0; t < 9; ++t) {
                uint4 w = WencP[t*68 + idx4];
                float sc = en[t];
                x[0] += sc*blo(w.x); x[1] += sc*bhi(w.x);
                x[2] += sc*blo(w.y); x[3] += sc*bhi(w.y);
                x[4] += sc*blo(w.z); x[5] += sc*bhi(w.z);
                x[6] += sc*blo(w.w); x[7] += sc*bhi(w.w);
            }
            s8v hfrag;
#pragma unroll
            for (int jj = 0; jj < 8; ++jj) hfrag[jj] = f2bs(silu_f(x[jj]));
            acc = __builtin_amdgcn_mfma_f32_16x16x32_bf16(hfrag, w2F[kc*64 + l], acc, 0, 0, 0);
        }
        // C-layout: col(channel)=l&15, row(edge)=qi*4+reg
#pragma unroll
        for (int reg = 0; reg < 4; ++reg) {
            float m = silu_f(acc[reg] + b2L[l & 15]);
            macc += m;
            int erow = hf*16 + qi*4 + reg;
            mL[wid][erow][l & 15] = f2bs(m);
        }
    }

    // ---- heads: S^T(64h x 32e) = cw1^T @ mL^T via 32x32x16 MFMA
    s8v mf = *(const s8v*)&mL[wid][l & 31][(l >> 5) * 8];   // B[k=ch][n=edge]
    f16v z;
#pragma unroll
    for (int i = 0; i < 16; ++i) z[i] = 0.f;

    float cwv, ccwv;
    {
        f16v C0 = __builtin_amdgcn_mfma_f32_32x32x16_bf16(cA0, mf, z, 0, 0, 0);
        f16v C1 = __builtin_amdgcn_mfma_f32_32x32x16_bf16(cA1, mf, z, 0, 0, 0);
        float val = 0.f;
#pragma unroll
        for (int reg = 0; reg < 16; ++reg) {
            int h = (reg & 3) + 8*(reg >> 2) + 4*(l >> 5);
            val += silu_f(C0[reg] + b1cL[h]) * cw2L[h];
            val += silu_f(C1[reg] + b1cL[h+32]) * cw2L[h+32];
        }
        val += __shfl_xor(val, 32, 64);
        cwv = val + coor_b2[0];
    }
    {
        f16v C0 = __builtin_amdgcn_mfma_f32_32x32x16_bf16(xA0, mf, z, 0, 0, 0);
        f16v C1 = __builtin_amdgcn_mfma_f32_32x32x16_bf16(xA1, mf, z, 0, 0, 0);
        float val = 0.f;
#pragma unroll
        for (int reg = 0; reg < 16; ++reg) {
            int h = (reg & 3) + 8*(reg >> 2) + 4*(l >> 5);
            val += silu_f(C0[reg] + b1xL[h]) * xw2L[h];
            val += silu_f(C1[reg] + b1xL[h+32]) * xw2L[h+32];
        }
        val += __shfl_xor(val, 32, 64);
        ccwv = val + cross_b2[0];
    }

    // ---- m_i: lane holds channel c=l&15 partial over 8 edges; sum quads
    macc += __shfl_xor(macc, 16, 64);
    macc += __shfl_xor(macc, 32, 64);
    if (l < 16) ws_mi[(size_t)r*MD + l] = macc;

    // ---- coordinate update: lane e=l (<32) weighted rel + cross
    float cxa = 0.f, cya = 0.f, cza = 0.f;
    if (l < 32) {
        int j = __float_as_int(encL[wid][l][9]);
        size_t jb = (size_t)((b << 11) | j) * 3;
        float cjx = coors[jb], cjy = coors[jb+1], cjz = coors[jb+2];
        float relx = cix - cjx, rely = ciy - cjy, relz = ciz - cjz;
        float cmjx = cjx - mx, cmjy = cjy - my, cmjz = cjz - mz;
        float crx = cmiy*cmjz - cmiz*cmjy;
        float cry = cmiz*cmjx - cmix*cmjz;
        float crz = cmix*cmjy - cmiy*cmjx;
        cxa = cwv*relx + ccwv*crx;
        cya = cwv*rely + ccwv*cry;
        cza = cwv*relz + ccwv*crz;
    }
#pragma unroll
    for (int mm = 1; mm < 64; mm <<= 1) {
        cxa += __shfl_xor(cxa, mm, 64);
        cya += __shfl_xor(cya, mm, 64);
        cza += __shfl_xor(cza, mm, 64);
    }
    if (l == 0) {
        out_coors[(size_t)r*3+0] = cix + cxa;
        out_coors[(size_t)r*3+1] = ciy + cya;
        out_coors[(size_t)r*3+2] = ciz + cza;
    }
}

// ---------------------------------------------------------------- node MLP (simple, f32)
__global__ __launch_bounds__(256) void node1_kernel(const float* __restrict__ feats,
                                                    const float* __restrict__ mi,
                                                    const float* __restrict__ w1,
                                                    const float* __restrict__ b1,
                                                    float* __restrict__ hidden) {
    int row = blockIdx.x;
    int col = threadIdx.x;
    float acc = b1[col];
    for (int k = 0; k < 128; ++k)
        acc += feats[(size_t)row*DD + k] * w1[(size_t)k*256 + col];
    for (int k = 0; k < 16; ++k)
        acc += mi[(size_t)row*MD + k] * w1[(size_t)(128+k)*256 + col];
    hidden[(size_t)row*256 + col] = silu_f(acc);
}

__global__ __launch_bounds__(128) void node2_kernel(const float* __restrict__ hidden,
                                                    const float* __restrict__ w2,
                                                    const float* __restrict__ b2,
                                                    const float* __restrict__ feats,
                                                    float* __restrict__ out_node) {
    int row = blockIdx.x;
    int col = threadIdx.x;
    float acc = b2[col];
    for (int k = 0; k < 256; ++k)
        acc += hidden[(size_t)row*256 + k] * w2[(size_t)k*DD + col];
    out_node[(size_t)row*DD + col] = acc + feats[(size_t)row*DD + col];
}

// ---------------------------------------------------------------- launch
// ws layout (<= 11.6 MB, proven safe):
//   [0,64)            ws_mean
//   [64, +1MB)        ws_idx
//   [1048640, +1MB)   ws_dist
//   [2097216, +512K)  ws_mi
//   [2621504, +8.9MB) ACall (4096 x 1088 bf16, per 2-batch chunk);
//                     hidden (8192x256 f32, 8MB) overlays after edges done.
extern "C" void kernel_launch(void* const* d_in, const int* in_sizes, int n_in,
                              void* d_out, int out_size, void* d_ws, size_t ws_size,
                              hipStream_t stream) {
    const float* feats    = (const float*)d_in[0];
    const float* coors    = (const float*)d_in[1];
    const float* edge_w1  = (const float*)d_in[2];
    const float* edge_b1  = (const float*)d_in[3];
    const float* edge_w2  = (const float*)d_in[4];
    const float* edge_b2  = (const float*)d_in[5];
    const float* coor_w1  = (const float*)d_in[6];
    const float* coor_b1  = (const float*)d_in[7];
    const float* coor_w2  = (const float*)d_in[8];
    const float* coor_b2  = (const float*)d_in[9];
    const float* cross_w1 = (const float*)d_in[10];
    const float* cross_b1 = (const float*)d_in[11];
    const float* cross_w2 = (const float*)d_in[12];
    const float* cross_b2 = (const float*)d_in[13];
    const float* node_w1  = (const float*)d_in[14];
    const float* node_b1  = (const float*)d_in[15];
    const float* node_w2  = (const float*)d_in[16];
    const float* node_b2  = (const float*)d_in[17];

    char* ws = (char*)d_ws;
    float* ws_mean = (float*)ws;
    int*   ws_idx  = (int*)(ws + 64);
    float* ws_dist = (float*)(ws + 1048640);
    float* ws_mi   = (float*)(ws + 2097216);
    bf16*  ACall   = (bf16*)(ws + 2621504);
    float* hidden  = (float*)(ws + 2621504);   // overlays ACall (dead by node1)

    float* out_node  = (float*)d_out;
    float* out_coors = out_node + (size_t)NROWS * DD;

    mean_kernel<<<BB, 256, 0, stream>>>(coors, ws_mean);
    topk_kernel<<<NROWS/4, 256, 0, stream>>>(coors, ws_idx, ws_dist);
    for (int c = 0; c < 2; ++c) {
        gemm_ac_kernel<<<dim3(17, 64), 256, 0, stream>>>(
            feats + (size_t)c*RCHUNK*DD, edge_w1, edge_b1, ACall);
        edge_kernel<<<RCHUNK/4, 256, 0, stream>>>(
            c, coors, ACall, ws_idx, ws_dist, ws_mean,
            edge_w1, edge_w2, edge_b2,
            coor_w1, coor_b1, coor_w2, coor_b2,
            cross_w1, cross_b1, cross_w2, cross_b2,
            ws_mi, out_coors);
    }
    node1_kernel<<<NROWS, 256, 0, stream>>>(feats, ws_mi, node_w1, node_b1, hidden);
    node2_kernel<<<NROWS, 128, 0, stream>>>(hidden, node_w2, node_b2, feats, out_node);
}

// Round 7
// 575.604 us; speedup vs baseline: 2.0891x; 1.1434x over previous
//
#include <hip/hip_runtime.h>
#include <hip/hip_bf16.h>

typedef __hip_bfloat16 bf16;
typedef __attribute__((ext_vector_type(8)))  short s8v;   // 8 bf16 (4 VGPRs)
typedef __attribute__((ext_vector_type(4)))  float f4v;
typedef __attribute__((ext_vector_type(16))) float f16v;

#define BB 4
#define NN 2048
#define DD 128
#define KK 32
#define MD 16
#define H1 530
#define HP 544            // padded hidden dim
#define WROW 1088         // ACall row: [ACa 544 | ACc 544]
#define NROWS (BB*NN)
#define RCHUNK 4096       // rows per 2-batch chunk

__device__ __forceinline__ float silu_f(float x) { return __fdividef(x, 1.0f + __expf(-x)); }
__device__ __forceinline__ float blo(unsigned u) { return __uint_as_float(u << 16); }
__device__ __forceinline__ float bhi(unsigned u) { return __uint_as_float(u & 0xffff0000u); }
__device__ __forceinline__ short f2bs(float x) { return (short)__bfloat16_as_ushort(__float2bfloat16(x)); }

// ---------------------------------------------------------------- mean kernel
__global__ __launch_bounds__(256) void mean_kernel(const float* __restrict__ coors,
                                                   float* __restrict__ ws_mean) {
    int b = blockIdx.x, tid = threadIdx.x;
    float sx = 0.f, sy = 0.f, sz = 0.f;
    const float* cb = coors + (size_t)b * NN * 3;
    for (int i = tid; i < NN; i += 256) {
        sx += cb[i*3+0]; sy += cb[i*3+1]; sz += cb[i*3+2];
    }
    __shared__ float sm[3][256];
    sm[0][tid] = sx; sm[1][tid] = sy; sm[2][tid] = sz;
    __syncthreads();
    for (int off = 128; off > 0; off >>= 1) {
        if (tid < off) {
            sm[0][tid] += sm[0][tid+off];
            sm[1][tid] += sm[1][tid+off];
            sm[2][tid] += sm[2][tid+off];
        }
        __syncthreads();
    }
    if (tid == 0) {
        ws_mean[b*3+0] = sm[0][0] * (1.f/NN);
        ws_mean[b*3+1] = sm[1][0] * (1.f/NN);
        ws_mean[b*3+2] = sm[2][0] * (1.f/NN);
    }
}

// ---------------------------------------------------------------- topk kernel (radix-select)
// one wave per row. keys = f32 bit patterns of squared distances (>=0 ->
// order-preserving). 31-round binary search for v32 = 32nd-smallest value
// (counts via ballot+popcount, SALU-side), then ballot-prefix compaction:
// strict winners, then ==v32 ties in ascending-j order (jax tiebreak).
__global__ __launch_bounds__(256) void topk_kernel(const float* __restrict__ coors,
                                                   int* __restrict__ ws_idx,
                                                   float* __restrict__ ws_dist) {
    __shared__ float cx[NN], cy[NN], cz[NN];
    int b = blockIdx.x >> 9;
    int grp = blockIdx.x & 511;
    const float* cb = coors + (size_t)b * NN * 3;
    for (int n = threadIdx.x; n < NN; n += 256) {
        cx[n] = cb[n*3+0]; cy[n] = cb[n*3+1]; cz[n] = cb[n*3+2];
    }
    __syncthreads();
    int lane = threadIdx.x & 63, wid = threadIdx.x >> 6;
    int i = grp*4 + wid;
    float ix = cx[i], iy = cy[i], iz = cz[i];
    unsigned keys[32];
#pragma unroll
    for (int s = 0; s < 32; ++s) {
        int j = s*64 + lane;
        float dx = ix - cx[j], dy = iy - cy[j], dz = iz - cz[j];
        float d = dx*dx + dy*dy + dz*dz;
        keys[s] = __float_as_uint(d);
    }
    // binary search on bit pattern (bit 31 = sign = 0 always)
    unsigned p = 0;
#pragma unroll 1
    for (int bit = 30; bit >= 0; --bit) {
        unsigned t = p | (1u << bit);
        int c = 0;
#pragma unroll
        for (int s = 0; s < 32; ++s)
            c += __popcll(__ballot(keys[s] < t));
        if (c < KK) p = t;
    }
    const unsigned v32 = p;
    int r = (b << 11) | i;
    int* oi = ws_idx + (size_t)r * KK;
    float* od = ws_dist + (size_t)r * KK;
    const unsigned long long lmask = (1ull << lane) - 1ull;
    int base = 0;
#pragma unroll
    for (int s = 0; s < 32; ++s) {           // strict winners (<= 31 of them)
        bool w = keys[s] < v32;
        unsigned long long mask = __ballot(w);
        int pre = __popcll(mask & lmask);
        if (w) { oi[base+pre] = s*64+lane; od[base+pre] = __uint_as_float(keys[s]); }
        base += __popcll(mask);
    }
#pragma unroll
    for (int s = 0; s < 32; ++s) {           // ties ==v32, ascending j
        if (base < KK) {
            bool w = (keys[s] == v32);
            unsigned long long mask = __ballot(w);
            int pre = __popcll(mask & lmask);
            int pos = base + pre;
            if (w && pos < KK) { oi[pos] = s*64+lane; od[pos] = __uint_as_float(v32); }
            base += __popcll(mask);
        }
    }
}

// ---------------------------------------------------------------- tiled f32 GEMM core
struct GemmSmem {
    float At[64][65];
    float Bt[64][64];
};

__device__ __forceinline__ void gemm_compute(GemmSmem* s, int tr, int tc, float acc[4][4]) {
#pragma unroll
    for (int kk = 0; kk < 64; ++kk) {
        float a0 = s->At[4*tr+0][kk];
        float a1 = s->At[4*tr+1][kk];
        float a2 = s->At[4*tr+2][kk];
        float a3 = s->At[4*tr+3][kk];
        float4 b4 = *reinterpret_cast<const float4*>(&s->Bt[kk][4*tc]);
        acc[0][0] += a0*b4.x; acc[0][1] += a0*b4.y; acc[0][2] += a0*b4.z; acc[0][3] += a0*b4.w;
        acc[1][0] += a1*b4.x; acc[1][1] += a1*b4.y; acc[1][2] += a1*b4.z; acc[1][3] += a1*b4.w;
        acc[2][0] += a2*b4.x; acc[2][1] += a2*b4.y; acc[2][2] += a2*b4.z; acc[2][3] += a2*b4.w;
        acc[3][0] += a3*b4.x; acc[3][1] += a3*b4.y; acc[3][2] += a3*b4.z; acc[3][3] += a3*b4.w;
    }
}

// ---------------------------------------------------------------- AC GEMM
// ACall[row][0..543]   = feats_row @ W1_top (+ b1), 544-padded
// ACall[row][544..1087]= feats_row @ W1_bot,        544-padded
__global__ __launch_bounds__(256) void gemm_ac_kernel(const float* __restrict__ feats_c,
                                                      const float* __restrict__ ew1,
                                                      const float* __restrict__ eb1,
                                                      bf16* __restrict__ ACall) {
    __shared__ GemmSmem s;
    int tid = threadIdx.x;
    int tc = tid & 15, tr = tid >> 4;
    int c0 = blockIdx.x * 64, r0 = blockIdx.y * 64;
    float acc[4][4] = {};
    for (int k0 = 0; k0 < 128; k0 += 64) {
#pragma unroll
        for (int it = 0; it < 16; ++it) {
            int e = it*256 + tid;
            int kk = e & 63, rr = e >> 6;
            s.At[rr][kk] = feats_c[(size_t)(r0+rr)*DD + k0 + kk];
        }
#pragma unroll
        for (int it = 0; it < 16; ++it) {
            int e = it*256 + tid;
            int cc = e & 63, kk = e >> 6;
            int cg = c0 + cc, kg = k0 + kk;
            float v = 0.f;
            if (cg < HP) { if (cg < H1) v = ew1[(size_t)kg*H1 + cg]; }
            else { int h = cg - HP; if (h < H1) v = ew1[(size_t)(128+kg)*H1 + h]; }
            s.Bt[kk][cc] = v;
        }
        __syncthreads();
        gemm_compute(&s, tr, tc, acc);
        __syncthreads();
    }
#pragma unroll
    for (int q = 0; q < 4; ++q) {
        int row = r0 + 4*tr + q;
#pragma unroll
        for (int u = 0; u < 4; ++u) {
            int cg = c0 + 4*tc + u;
            float bias = (cg < H1) ? eb1[cg] : 0.f;
            ACall[(size_t)row*WROW + cg] = __float2bfloat16(acc[q][u] + bias);
        }
    }
}

// ---------------------------------------------------------------- edge kernel (MFMA)
__global__ __launch_bounds__(256, 3) void edge_kernel(
    int chunk,
    const float* __restrict__ coors, const bf16* __restrict__ ACall,
    const int* __restrict__ ws_idx, const float* __restrict__ ws_dist,
    const float* __restrict__ ws_mean,
    const float* __restrict__ edge_w1, const float* __restrict__ edge_w2,
    const float* __restrict__ edge_b2,
    const float* __restrict__ coor_w1, const float* __restrict__ coor_b1,
    const float* __restrict__ coor_w2, const float* __restrict__ coor_b2,
    const float* __restrict__ cross_w1, const float* __restrict__ cross_b1,
    const float* __restrict__ cross_w2, const float* __restrict__ cross_b2,
    float* __restrict__ ws_mi, float* __restrict__ out_coors) {

    __shared__ s8v  w2F[1088];                 // W2 B-frags, [kc][lane]
    __shared__ uint4 WencP[612];               // Wenc bf16-packed [t][68]
    __shared__ uint4 aL[4][68];                // per-wave ACa row (544 bf16)
    __shared__ __align__(16) short mL[4][32][16]; // per-wave m (bf16)
    __shared__ float encL[4][32][12];          // per-wave enc + j
    __shared__ float b1cL[64], b1xL[64], cw2L[64], xw2L[64], b2L[16];

    int tid = threadIdx.x, l = tid & 63, wid = tid >> 6;

    for (int s = tid; s < 1088; s += 256) {
        int kc = s >> 6, ln = s & 63;
        int kb = kc*32 + ((ln >> 4) * 8), c = ln & 15;
        s8v t;
#pragma unroll
        for (int j = 0; j < 8; ++j) {
            int k = kb + j;
            float v = (k < H1) ? edge_w2[(size_t)k*MD + c] : 0.f;
            t[j] = f2bs(v);
        }
        w2F[s] = t;
    }
    for (int s = tid; s < 612; s += 256) {
        int tt = s / 68, q = s % 68;
        uint4 u;
        unsigned* pu = (unsigned*)&u;
#pragma unroll
        for (int p = 0; p < 4; ++p) {
            int k0 = q*8 + p*2;
            float v0 = (k0   < H1) ? edge_w1[(size_t)(256+tt)*H1 + k0]   : 0.f;
            float v1 = (k0+1 < H1) ? edge_w1[(size_t)(256+tt)*H1 + k0+1] : 0.f;
            pu[p] = (unsigned)(unsigned short)__bfloat16_as_ushort(__float2bfloat16(v0))
                  | ((unsigned)(unsigned short)__bfloat16_as_ushort(__float2bfloat16(v1)) << 16);
        }
        WencP[s] = u;
    }
    if (tid < 64) {
        b1cL[tid] = coor_b1[tid]; b1xL[tid] = cross_b1[tid];
        cw2L[tid] = coor_w2[tid]; xw2L[tid] = cross_w2[tid];
    }
    if (tid < 16) b2L[tid] = edge_b2[tid];
    __syncthreads();

    s8v cA0, cA1, xA0, xA1;
    {
        int hb = l & 31, ks = (l >> 5) * 8;
#pragma unroll
        for (int j = 0; j < 8; ++j) {
            int ch = ks + j;
            cA0[j] = f2bs(coor_w1[(size_t)ch*64 + hb]);
            cA1[j] = f2bs(coor_w1[(size_t)ch*64 + hb + 32]);
            xA0[j] = f2bs(cross_w1[(size_t)ch*64 + hb]);
            xA1[j] = f2bs(cross_w1[(size_t)ch*64 + hb + 32]);
        }
    }

    int r_local = blockIdx.x*4 + wid;
    int b = chunk*2 + (r_local >> 11);
    int r = (b << 11) | (r_local & 2047);

    const uint4* rowA4 = (const uint4*)(ACall + (size_t)r_local * WROW);
    aL[wid][l] = rowA4[l < 68 ? l : 0];
    if (l < 4) aL[wid][l + 64] = rowA4[l + 64];

    float mx = ws_mean[b*3+0], my = ws_mean[b*3+1], mz = ws_mean[b*3+2];
    float cix = coors[(size_t)r*3+0], ciy = coors[(size_t)r*3+1], ciz = coors[(size_t)r*3+2];
    float cmix = cix-mx, cmiy = ciy-my, cmiz = ciz-mz;

    const int* idxr = ws_idx + (size_t)r * KK;
    const float* distr = ws_dist + (size_t)r * KK;
    if (l < 32) {
        float d = distr[l];
        encL[wid][l][0] = __sinf(d);
        encL[wid][l][1] = __sinf(d*0.5f);
        encL[wid][l][2] = __sinf(d*0.25f);
        encL[wid][l][3] = __sinf(d*0.125f);
        encL[wid][l][4] = __cosf(d);
        encL[wid][l][5] = __cosf(d*0.5f);
        encL[wid][l][6] = __cosf(d*0.25f);
        encL[wid][l][7] = __cosf(d*0.125f);
        encL[wid][l][8] = d;
        encL[wid][l][9] = __int_as_float(idxr[l]);
    }

    float macc = 0.f;
    const int qi = l >> 4;

#pragma unroll 1
    for (int hf = 0; hf < 2; ++hf) {
        int e = hf*16 + (l & 15);
        float en[9];
#pragma unroll
        for (int t = 0; t < 9; ++t) en[t] = encL[wid][e][t];
        int j = __float_as_int(encL[wid][e][9]);
        int jrow = ((r_local >> 11) << 11) | j;
        const uint4* cPtr = (const uint4*)(ACall + (size_t)jrow*WROW + HP);

        f4v acc = {0.f, 0.f, 0.f, 0.f};
#pragma unroll 1
        for (int kc = 0; kc < 17; ++kc) {
            int idx4 = kc*4 + qi;
            uint4 aA = aL[wid][idx4];
            uint4 cC = cPtr[idx4];
            float x[8];
            x[0]=blo(aA.x)+blo(cC.x); x[1]=bhi(aA.x)+bhi(cC.x);
            x[2]=blo(aA.y)+blo(cC.y); x[3]=bhi(aA.y)+bhi(cC.y);
            x[4]=blo(aA.z)+blo(cC.z); x[5]=bhi(aA.z)+bhi(cC.z);
            x[6]=blo(aA.w)+blo(cC.w); x[7]=bhi(aA.w)+bhi(cC.w);
#pragma unroll
            for (int t = 0; t < 9; ++t) {
                uint4 w = WencP[t*68 + idx4];
                float sc = en[t];
                x[0] += sc*blo(w.x); x[1] += sc*bhi(w.x);
                x[2] += sc*blo(w.y); x[3] += sc*bhi(w.y);
                x[4] += sc*blo(w.z); x[5] += sc*bhi(w.z);
                x[6] += sc*blo(w.w); x[7] += sc*bhi(w.w);
            }
            s8v hfrag;
#pragma unroll
            for (int jj = 0; jj < 8; ++jj) hfrag[jj] = f2bs(silu_f(x[jj]));
            acc = __builtin_amdgcn_mfma_f32_16x16x32_bf16(hfrag, w2F[kc*64 + l], acc, 0, 0, 0);
        }
#pragma unroll
        for (int reg = 0; reg < 4; ++reg) {
            float m = silu_f(acc[reg] + b2L[l & 15]);
            macc += m;
            int erow = hf*16 + qi*4 + reg;
            mL[wid][erow][l & 15] = f2bs(m);
        }
    }

    s8v mf = *(const s8v*)&mL[wid][l & 31][(l >> 5) * 8];
    f16v z;
#pragma unroll
    for (int i = 0; i < 16; ++i) z[i] = 0.f;

    float cwv, ccwv;
    {
        f16v C0 = __builtin_amdgcn_mfma_f32_32x32x16_bf16(cA0, mf, z, 0, 0, 0);
        f16v C1 = __builtin_amdgcn_mfma_f32_32x32x16_bf16(cA1, mf, z, 0, 0, 0);
        float val = 0.f;
#pragma unroll
        for (int reg = 0; reg < 16; ++reg) {
            int h = (reg & 3) + 8*(reg >> 2) + 4*(l >> 5);
            val += silu_f(C0[reg] + b1cL[h]) * cw2L[h];
            val += silu_f(C1[reg] + b1cL[h+32]) * cw2L[h+32];
        }
        val += __shfl_xor(val, 32, 64);
        cwv = val + coor_b2[0];
    }
    {
        f16v C0 = __builtin_amdgcn_mfma_f32_32x32x16_bf16(xA0, mf, z, 0, 0, 0);
        f16v C1 = __builtin_amdgcn_mfma_f32_32x32x16_bf16(xA1, mf, z, 0, 0, 0);
        float val = 0.f;
#pragma unroll
        for (int reg = 0; reg < 16; ++reg) {
            int h = (reg & 3) + 8*(reg >> 2) + 4*(l >> 5);
            val += silu_f(C0[reg] + b1xL[h]) * xw2L[h];
            val += silu_f(C1[reg] + b1xL[h+32]) * xw2L[h+32];
        }
        val += __shfl_xor(val, 32, 64);
        ccwv = val + cross_b2[0];
    }

    macc += __shfl_xor(macc, 16, 64);
    macc += __shfl_xor(macc, 32, 64);
    if (l < 16) ws_mi[(size_t)r*MD + l] = macc;

    float cxa = 0.f, cya = 0.f, cza = 0.f;
    if (l < 32) {
        int j = __float_as_int(encL[wid][l][9]);
        size_t jb = (size_t)((b << 11) | j) * 3;
        float cjx = coors[jb], cjy = coors[jb+1], cjz = coors[jb+2];
        float relx = cix - cjx, rely = ciy - cjy, relz = ciz - cjz;
        float cmjx = cjx - mx, cmjy = cjy - my, cmjz = cjz - mz;
        float crx = cmiy*cmjz - cmiz*cmjy;
        float cry = cmiz*cmjx - cmix*cmjz;
        float crz = cmix*cmjy - cmiy*cmjx;
        cxa = cwv*relx + ccwv*crx;
        cya = cwv*rely + ccwv*cry;
        cza = cwv*relz + ccwv*crz;
    }
#pragma unroll
    for (int mm = 1; mm < 64; mm <<= 1) {
        cxa += __shfl_xor(cxa, mm, 64);
        cya += __shfl_xor(cya, mm, 64);
        cza += __shfl_xor(cza, mm, 64);
    }
    if (l == 0) {
        out_coors[(size_t)r*3+0] = cix + cxa;
        out_coors[(size_t)r*3+1] = ciy + cya;
        out_coors[(size_t)r*3+2] = ciz + cza;
    }
}

// ---------------------------------------------------------------- node MLP GEMM 1 (tiled)
// hidden = silu([feats | m_i](8192x144) @ node_w1(144x256) + b1)
__global__ __launch_bounds__(256) void node1_kernel(const float* __restrict__ feats,
                                                    const float* __restrict__ mi,
                                                    const float* __restrict__ w1,
                                                    const float* __restrict__ b1,
                                                    float* __restrict__ hidden) {
    __shared__ GemmSmem s;
    int tid = threadIdx.x;
    int tc = tid & 15, tr = tid >> 4;
    int c0 = blockIdx.x * 64, r0 = blockIdx.y * 64;
    float acc[4][4] = {};
    for (int k0 = 0; k0 < 144; k0 += 64) {
#pragma unroll
        for (int it = 0; it < 16; ++it) {
            int e = it*256 + tid;
            int kk = e & 63, rr = e >> 6;
            int kg = k0 + kk;
            float v;
            if (kg < 128)      v = feats[(size_t)(r0+rr)*DD + kg];
            else if (kg < 144) v = mi[(size_t)(r0+rr)*MD + (kg-128)];
            else               v = 0.f;
            s.At[rr][kk] = v;
        }
#pragma unroll
        for (int it = 0; it < 16; ++it) {
            int e = it*256 + tid;
            int cc = e & 63, kk = e >> 6;
            int kg = k0 + kk;
            s.Bt[kk][cc] = (kg < 144) ? w1[(size_t)kg*256 + c0 + cc] : 0.f;
        }
        __syncthreads();
        gemm_compute(&s, tr, tc, acc);
        __syncthreads();
    }
#pragma unroll
    for (int q = 0; q < 4; ++q) {
        int row = r0 + 4*tr + q;
#pragma unroll
        for (int u = 0; u < 4; ++u) {
            int col = c0 + 4*tc + u;
            hidden[(size_t)row*256 + col] = silu_f(acc[q][u] + b1[col]);
        }
    }
}

// ---------------------------------------------------------------- node MLP GEMM 2 (tiled)
// out = hidden(8192x256) @ node_w2(256x128) + b2 + feats
__global__ __launch_bounds__(256) void node2_kernel(const float* __restrict__ hidden,
                                                    const float* __restrict__ w2,
                                                    const float* __restrict__ b2,
                                                    const float* __restrict__ feats,
                                                    float* __restrict__ out_node) {
    __shared__ GemmSmem s;
    int tid = threadIdx.x;
    int tc = tid & 15, tr = tid >> 4;
    int c0 = blockIdx.x * 64, r0 = blockIdx.y * 64;
    float acc[4][4] = {};
    for (int k0 = 0; k0 < 256; k0 += 64) {
#pragma unroll
        for (int it = 0; it < 16; ++it) {
            int e = it*256 + tid;
            int kk = e & 63, rr = e >> 6;
            s.At[rr][kk] = hidden[(size_t)(r0+rr)*256 + k0 + kk];
        }
#pragma unroll
        for (int it = 0; it < 16; ++it) {
            int e = it*256 + tid;
            int cc = e & 63, kk = e >> 6;
            s.Bt[kk][cc] = w2[(size_t)(k0+kk)*DD + c0 + cc];
        }
        __syncthreads();
        gemm_compute(&s, tr, tc, acc);
        __syncthreads();
    }
#pragma unroll
    for (int q = 0; q < 4; ++q) {
        int row = r0 + 4*tr + q;
#pragma unroll
        for (int u = 0; u < 4; ++u) {
            int col = c0 + 4*tc + u;
            out_node[(size_t)row*DD + col] = acc[q][u] + b2[col] + feats[(size_t)row*DD + col];
        }
    }
}

// ---------------------------------------------------------------- launch
// ws layout (<= 11.6 MB):
//   [0,64)            ws_mean
//   [64, +1MB)        ws_idx
//   [1048640, +1MB)   ws_dist
//   [2097216, +512K)  ws_mi
//   [2621504, +8.9MB) ACall (4096 x 1088 bf16, per 2-batch chunk);
//                     hidden (8192x256 f32, 8MB) overlays after edges done.
extern "C" void kernel_launch(void* const* d_in, const int* in_sizes, int n_in,
                              void* d_out, int out_size, void* d_ws, size_t ws_size,
                              hipStream_t stream) {
    const float* feats    = (const float*)d_in[0];
    const float* coors    = (const float*)d_in[1];
    const float* edge_w1  = (const float*)d_in[2];
    const float* edge_b1  = (const float*)d_in[3];
    const float* edge_w2  = (const float*)d_in[4];
    const float* edge_b2  = (const float*)d_in[5];
    const float* coor_w1  = (const float*)d_in[6];
    const float* coor_b1  = (const float*)d_in[7];
    const float* coor_w2  = (const float*)d_in[8];
    const float* coor_b2  = (const float*)d_in[9];
    const float* cross_w1 = (const float*)d_in[10];
    const float* cross_b1 = (const float*)d_in[11];
    const float* cross_w2 = (const float*)d_in[12];
    const float* cross_b2 = (const float*)d_in[13];
    const float* node_w1  = (const float*)d_in[14];
    const float* node_b1  = (const float*)d_in[15];
    const float* node_w2  = (const float*)d_in[16];
    const float* node_b2  = (const float*)d_in[17];

    char* ws = (char*)d_ws;
    float* ws_mean = (float*)ws;
    int*   ws_idx  = (int*)(ws + 64);
    float* ws_dist = (float*)(ws + 1048640);
    float* ws_mi   = (float*)(ws + 2097216);
    bf16*  ACall   = (bf16*)(ws + 2621504);
    float* hidden  = (float*)(ws + 2621504);   // overlays ACall (dead by node1)

    float* out_node  = (float*)d_out;
    float* out_coors = out_node + (size_t)NROWS * DD;

    mean_kernel<<<BB, 256, 0, stream>>>(coors, ws_mean);
    topk_kernel<<<NROWS/4, 256, 0, stream>>>(coors, ws_idx, ws_dist);
    for (int c = 0; c < 2; ++c) {
        gemm_ac_kernel<<<dim3(17, 64), 256, 0, stream>>>(
            feats + (size_t)c*RCHUNK*DD, edge_w1, edge_b1, ACall);
        edge_kernel<<<RCHUNK/4, 256, 0, stream>>>(
            c, coors, ACall, ws_idx, ws_dist, ws_mean,
            edge_w1, edge_w2, edge_b2,
            coor_w1, coor_b1, coor_w2, coor_b2,
            cross_w1, cross_b1, cross_w2, cross_b2,
            ws_mi, out_coors);
    }
    node1_kernel<<<dim3(4, NROWS/64), 256, 0, stream>>>(feats, ws_mi, node_w1, node_b1, hidden);
    node2_kernel<<<dim3(2, NROWS/64), 256, 0, stream>>>(hidden, node_w2, node_b2, feats, out_node);
}

// Round 8
// 350.853 us; speedup vs baseline: 3.4273x; 1.6406x over previous
//
#include <hip/hip_runtime.h>
#include <hip/hip_bf16.h>

typedef __hip_bfloat16 bf16;
typedef __attribute__((ext_vector_type(8)))  short s8v;   // 8 bf16 (4 VGPRs)
typedef __attribute__((ext_vector_type(4)))  float f4v;
typedef __attribute__((ext_vector_type(16))) float f16v;

#define BB 4
#define NN 2048
#define DD 128
#define KK 32
#define MD 16
#define H1 530
#define HP 544            // padded hidden dim
#define WROW 1088         // ACall row: [ACa 544 | ACc 544]
#define NROWS (BB*NN)
#define RCHUNK 4096       // rows per 2-batch chunk

__device__ __forceinline__ float silu_f(float x) { return __fdividef(x, 1.0f + __expf(-x)); }
__device__ __forceinline__ float blo(unsigned u) { return __uint_as_float(u << 16); }
__device__ __forceinline__ float bhi(unsigned u) { return __uint_as_float(u & 0xffff0000u); }
__device__ __forceinline__ short f2bs(float x) { return (short)__bfloat16_as_ushort(__float2bfloat16(x)); }
__device__ __forceinline__ unsigned packbf(float a, float b) {
    unsigned ua = (unsigned short)__bfloat16_as_ushort(__float2bfloat16(a));
    unsigned ub = (unsigned short)__bfloat16_as_ushort(__float2bfloat16(b));
    return ua | (ub << 16);
}

// ---------------------------------------------------------------- topk kernel (radix-select) + fused mean
__global__ __launch_bounds__(256) void topk_kernel(const float* __restrict__ coors,
                                                   int* __restrict__ ws_idx,
                                                   float* __restrict__ ws_dist,
                                                   float* __restrict__ ws_mean) {
    __shared__ float cx[NN], cy[NN], cz[NN];
    __shared__ float redw[12];
    int b = blockIdx.x >> 9;
    int grp = blockIdx.x & 511;
    const float* cb = coors + (size_t)b * NN * 3;
    for (int n = threadIdx.x; n < NN; n += 256) {
        cx[n] = cb[n*3+0]; cy[n] = cb[n*3+1]; cz[n] = cb[n*3+2];
    }
    __syncthreads();
    int lane = threadIdx.x & 63, wid = threadIdx.x >> 6;

    if (grp == 0) {     // fused per-batch mean (block-uniform branch)
        float sx = 0.f, sy = 0.f, sz = 0.f;
        for (int n = threadIdx.x; n < NN; n += 256) { sx += cx[n]; sy += cy[n]; sz += cz[n]; }
#pragma unroll
        for (int mm = 1; mm < 64; mm <<= 1) {
            sx += __shfl_xor(sx, mm, 64);
            sy += __shfl_xor(sy, mm, 64);
            sz += __shfl_xor(sz, mm, 64);
        }
        if (lane == 0) { redw[wid*3+0] = sx; redw[wid*3+1] = sy; redw[wid*3+2] = sz; }
        __syncthreads();
        if (threadIdx.x < 3) {
            ws_mean[b*3 + threadIdx.x] =
                (redw[threadIdx.x] + redw[3+threadIdx.x] + redw[6+threadIdx.x] + redw[9+threadIdx.x]) * (1.f/NN);
        }
    }

    int i = grp*4 + wid;
    float ix = cx[i], iy = cy[i], iz = cz[i];
    unsigned keys[32];
#pragma unroll
    for (int s = 0; s < 32; ++s) {
        int j = s*64 + lane;
        float dx = ix - cx[j], dy = iy - cy[j], dz = iz - cz[j];
        float d = dx*dx + dy*dy + dz*dz;
        keys[s] = __float_as_uint(d);   // d >= 0 -> order-preserving
    }
    unsigned p = 0;
#pragma unroll 1
    for (int bit = 30; bit >= 0; --bit) {
        unsigned t = p | (1u << bit);
        int c = 0;
#pragma unroll
        for (int s = 0; s < 32; ++s)
            c += __popcll(__ballot(keys[s] < t));
        if (c < KK) p = t;
    }
    const unsigned v32 = p;
    int r = (b << 11) | i;
    int* oi = ws_idx + (size_t)r * KK;
    float* od = ws_dist + (size_t)r * KK;
    const unsigned long long lmask = (1ull << lane) - 1ull;
    int base = 0;
#pragma unroll
    for (int s = 0; s < 32; ++s) {
        bool w = keys[s] < v32;
        unsigned long long mask = __ballot(w);
        int pre = __popcll(mask & lmask);
        if (w) { oi[base+pre] = s*64+lane; od[base+pre] = __uint_as_float(keys[s]); }
        base += __popcll(mask);
    }
#pragma unroll
    for (int s = 0; s < 32; ++s) {
        if (base < KK) {
            bool w = (keys[s] == v32);
            unsigned long long mask = __ballot(w);
            int pre = __popcll(mask & lmask);
            int pos = base + pre;
            if (w && pos < KK) { oi[pos] = s*64+lane; od[pos] = __uint_as_float(v32); }
            base += __popcll(mask);
        }
    }
}

// ---------------------------------------------------------------- generic MFMA GEMM (64x64 tile, 4 waves)
// MODE 0: ACall = featsChunk(4096x128) @ [W1_top|W1_bot] (+b1 on A-part), bf16 out
// MODE 1: hiddenB = silu([feats|mi](8192x144) @ w1 + b1), bf16 out
// MODE 2: out_node = hiddenB(8192x256) @ w2 + b2 + feats, f32 out
template<int MODE>
__global__ __launch_bounds__(256) void mfma_gemm_kernel(
    const float* __restrict__ pa, const float* __restrict__ pa2,
    const bf16* __restrict__ paB, const float* __restrict__ pb,
    const float* __restrict__ pbias, const float* __restrict__ pskip,
    bf16* __restrict__ poutB, float* __restrict__ poutF) {

    constexpr int KTOT  = (MODE==0) ? 128 : (MODE==1) ? 144 : 256;
    constexpr int KPAD  = (MODE==0) ? 128 : (MODE==1) ? 160 : 256;
    constexpr int PITCH = KPAD + 8;
    __shared__ __align__(16) short Bs[64][PITCH];

    int tid = threadIdx.x, l = tid & 63, w = tid >> 6, q = l >> 4;
    int c0 = blockIdx.x * 64, r0 = blockIdx.y * 64;

    for (int idx = tid; idx < 64*KTOT; idx += 256) {
        int n = idx & 63, k = idx >> 6;
        float v;
        if constexpr (MODE == 0) {
            int cg = c0 + n;
            if (cg < HP) v = (cg < H1) ? pb[(size_t)k*H1 + cg] : 0.f;
            else { int h = cg - HP; v = (h < H1) ? pb[(size_t)(128+k)*H1 + h] : 0.f; }
        } else if constexpr (MODE == 1) {
            v = pb[(size_t)k*256 + c0 + n];
        } else {
            v = pb[(size_t)k*DD + c0 + n];
        }
        Bs[n][k] = f2bs(v);
    }
    if constexpr (KPAD > KTOT) {
        for (int idx = tid; idx < 64*(KPAD-KTOT); idx += 256) {
            int n = idx >> 4, k = KTOT + (idx & 15);
            Bs[n][k] = 0;
        }
    }
    __syncthreads();

    int m = r0 + w*16 + (l & 15);
    f4v z4 = {0.f, 0.f, 0.f, 0.f};
    f4v acc[4] = {z4, z4, z4, z4};
#pragma unroll
    for (int kc = 0; kc < KPAD/32; ++kc) {
        int k0 = kc*32 + q*8;
        s8v af;
        if constexpr (MODE == 2) {
            af = *(const s8v*)(paB + (size_t)m*256 + k0);
        } else if constexpr (MODE == 0) {
            float4 f0 = *(const float4*)(pa + (size_t)m*DD + k0);
            float4 f1 = *(const float4*)(pa + (size_t)m*DD + k0 + 4);
            af[0]=f2bs(f0.x); af[1]=f2bs(f0.y); af[2]=f2bs(f0.z); af[3]=f2bs(f0.w);
            af[4]=f2bs(f1.x); af[5]=f2bs(f1.y); af[6]=f2bs(f1.z); af[7]=f2bs(f1.w);
        } else {
            if (k0 + 8 <= 128) {
                float4 f0 = *(const float4*)(pa + (size_t)m*DD + k0);
                float4 f1 = *(const float4*)(pa + (size_t)m*DD + k0 + 4);
                af[0]=f2bs(f0.x); af[1]=f2bs(f0.y); af[2]=f2bs(f0.z); af[3]=f2bs(f0.w);
                af[4]=f2bs(f1.x); af[5]=f2bs(f1.y); af[6]=f2bs(f1.z); af[7]=f2bs(f1.w);
            } else {
#pragma unroll
                for (int j = 0; j < 8; ++j) {
                    int kk = k0 + j;
                    float v = (kk < 128) ? pa[(size_t)m*DD + kk]
                            : (kk < 144) ? pa2[(size_t)m*MD + (kk-128)] : 0.f;
                    af[j] = f2bs(v);
                }
            }
        }
#pragma unroll
        for (int cc = 0; cc < 4; ++cc) {
            s8v bf = *(const s8v*)&Bs[cc*16 + (l & 15)][k0];
            acc[cc] = __builtin_amdgcn_mfma_f32_16x16x32_bf16(af, bf, acc[cc], 0, 0, 0);
        }
    }
#pragma unroll
    for (int cc = 0; cc < 4; ++cc) {
        int col = c0 + cc*16 + (l & 15);
#pragma unroll
        for (int reg = 0; reg < 4; ++reg) {
            int row = r0 + w*16 + q*4 + reg;
            float v = acc[cc][reg];
            if constexpr (MODE == 0) {
                float bias = (col < H1) ? pbias[col] : 0.f;
                poutB[(size_t)row*WROW + col] = __float2bfloat16(v + bias);
            } else if constexpr (MODE == 1) {
                poutB[(size_t)row*256 + col] = __float2bfloat16(silu_f(v + pbias[col]));
            } else {
                poutF[(size_t)row*DD + col] = v + pbias[col] + pskip[(size_t)row*DD + col];
            }
        }
    }
}

// ---------------------------------------------------------------- edge kernel (full MFMA)
// Per kc: 2x enc-MFMA (Y = Wenc^T-frag @ enc-frag, K=32 pad) -> +a +c, silu, pack
// -> 8-shuffle layout repair -> W2 MFMA. Heads via 32x32x16 as before.
__global__ __launch_bounds__(256, 4) void edge_kernel(
    int chunk,
    const float* __restrict__ coors, const bf16* __restrict__ ACall,
    const int* __restrict__ ws_idx, const float* __restrict__ ws_dist,
    const float* __restrict__ ws_mean,
    const float* __restrict__ edge_w1, const float* __restrict__ edge_w2,
    const float* __restrict__ edge_b2,
    const float* __restrict__ coor_w1, const float* __restrict__ coor_b1,
    const float* __restrict__ coor_w2, const float* __restrict__ coor_b2,
    const float* __restrict__ cross_w1, const float* __restrict__ cross_b1,
    const float* __restrict__ cross_w2, const float* __restrict__ cross_b2,
    float* __restrict__ ws_mi, float* __restrict__ out_coors) {

    __shared__ s8v  w2F[1088];                    // W2 B-frags [kc][lane]          17408 B
    __shared__ s8v  WencF[34*16];                 // enc A-frags quad0 [chunk][h']   8704 B
    __shared__ short WdF[34*16];                  // enc A-frag quad1 elem0 (t=8)    1088 B
    __shared__ __align__(16) short aS[4][544];    // per-wave ACa row (b1 baked)     4352 B
    __shared__ __align__(16) short mL[4][32][16]; // per-wave m (bf16)               4096 B
    __shared__ float b1cL[64], b1xL[64], cw2L[64], xw2L[64], b2L[16];
    // total ~36.7 KB -> 4 blocks/CU

    int tid = threadIdx.x, l = tid & 63, wid = tid >> 6;
    const int q = l >> 4, e15 = l & 15;

    for (int s = tid; s < 1088; s += 256) {
        int kc = s >> 6, ln = s & 63;
        int kb = kc*32 + ((ln >> 4) * 8), c = ln & 15;
        s8v t;
#pragma unroll
        for (int j = 0; j < 8; ++j) {
            int k = kb + j;
            t[j] = (k < H1) ? f2bs(edge_w2[(size_t)k*MD + c]) : (short)0;
        }
        w2F[s] = t;
    }
    for (int s = tid; s < 544; s += 256) {
        int ch = s >> 4, hp = s & 15;
        int h = ch*16 + hp;
        s8v t;
#pragma unroll
        for (int j = 0; j < 8; ++j)
            t[j] = (h < H1) ? f2bs(edge_w1[(size_t)(256+j)*H1 + h]) : (short)0;
        WencF[s] = t;
        WdF[s] = (h < H1) ? f2bs(edge_w1[(size_t)264*H1 + h]) : (short)0;
    }
    if (tid < 64) {
        b1cL[tid] = coor_b1[tid]; b1xL[tid] = cross_b1[tid];
        cw2L[tid] = coor_w2[tid]; xw2L[tid] = cross_w2[tid];
    }
    if (tid < 16) b2L[tid] = edge_b2[tid];
    __syncthreads();

    // head A-frags (32x32x16 layout, same as verified round-6 kernel)
    s8v cA0, cA1, xA0, xA1;
    {
        int hb = l & 31, ks = (l >> 5) * 8;
#pragma unroll
        for (int j = 0; j < 8; ++j) {
            int ch = ks + j;
            cA0[j] = f2bs(coor_w1[(size_t)ch*64 + hb]);
            cA1[j] = f2bs(coor_w1[(size_t)ch*64 + hb + 32]);
            xA0[j] = f2bs(cross_w1[(size_t)ch*64 + hb]);
            xA1[j] = f2bs(cross_w1[(size_t)ch*64 + hb + 32]);
        }
    }

    int r_local = blockIdx.x*4 + wid;
    int b = chunk*2 + (r_local >> 11);
    int r = (b << 11) | (r_local & 2047);

    const uint4* rowA4 = (const uint4*)(ACall + (size_t)r_local * WROW);
    ((uint4*)aS[wid])[l < 68 ? l : 0] = rowA4[l < 68 ? l : 0];
    if (l < 4) ((uint4*)aS[wid])[l + 64] = rowA4[l + 64];

    float mx = ws_mean[b*3+0], my = ws_mean[b*3+1], mz = ws_mean[b*3+2];
    float cix = coors[(size_t)r*3+0], ciy = coors[(size_t)r*3+1], ciz = coors[(size_t)r*3+2];
    float cmix = cix-mx, cmiy = ciy-my, cmiz = ciz-mz;

    const int* idxr = ws_idx + (size_t)r * KK;
    const float* distr = ws_dist + (size_t)r * KK;
    int le = l & 31;
    float dme = distr[le];
    int jv = idxr[le];
    float en0 = __sinf(dme),        en1 = __sinf(dme*0.5f);
    float en2 = __sinf(dme*0.25f),  en3 = __sinf(dme*0.125f);
    float en4 = __cosf(dme),        en5 = __cosf(dme*0.5f);
    float en6 = __cosf(dme*0.25f),  en7 = __cosf(dme*0.125f);

    float macc = 0.f;
    const f4v z4 = {0.f, 0.f, 0.f, 0.f};
    const int srcA = ((q & 1) * 32) + e15;
    const int srcB = srcA + 16;
    const bool hiC = (q >= 2);
    const int batch_base = (r_local >> 11) << 11;

#pragma unroll 1
    for (int hf = 0; hf < 2; ++hf) {
        int src0 = hf*16 + e15;
        float g0 = __shfl(en0, src0, 64), g1 = __shfl(en1, src0, 64);
        float g2 = __shfl(en2, src0, 64), g3 = __shfl(en3, src0, 64);
        float g4 = __shfl(en4, src0, 64), g5 = __shfl(en5, src0, 64);
        float g6 = __shfl(en6, src0, 64), g7 = __shfl(en7, src0, 64);
        float g8 = __shfl(dme, src0, 64);
        int jj = __shfl(jv, src0, 64);

        s8v encB = {0,0,0,0,0,0,0,0};
        if (q == 0) {
            encB[0]=f2bs(g0); encB[1]=f2bs(g1); encB[2]=f2bs(g2); encB[3]=f2bs(g3);
            encB[4]=f2bs(g4); encB[5]=f2bs(g5); encB[6]=f2bs(g6); encB[7]=f2bs(g7);
        } else if (q == 1) {
            encB[0] = f2bs(g8);
        }

        int jrow = batch_base | jj;
        const char* cBase = (const char*)(ACall + (size_t)jrow*WROW + HP);

        f4v acc = z4;
#pragma unroll 1
        for (int kc = 0; kc < 17; ++kc) {
            unsigned P00, P01, P10, P11;
#pragma unroll
            for (int c = 0; c < 2; ++c) {
                int ch = kc*2 + c;
                s8v afr = {0,0,0,0,0,0,0,0};
                if (q == 0) afr = WencF[(ch << 4) | e15];
                else if (q == 1) afr[0] = WdF[(ch << 4) | e15];
                f4v Y = __builtin_amdgcn_mfma_f32_16x16x32_bf16(afr, encB, z4, 0, 0, 0);
                int hb = kc*32 + c*16 + q*4;
                uint2 av = *(const uint2*)&aS[wid][hb];
                uint2 cv = *(const uint2*)(cBase + (size_t)hb*2);
                float x0 = silu_f(Y[0] + blo(av.x) + blo(cv.x));
                float x1 = silu_f(Y[1] + bhi(av.x) + bhi(cv.x));
                float x2 = silu_f(Y[2] + blo(av.y) + blo(cv.y));
                float x3 = silu_f(Y[3] + bhi(av.y) + bhi(cv.y));
                if (c == 0) { P00 = packbf(x0, x1); P01 = packbf(x2, x3); }
                else        { P10 = packbf(x0, x1); P11 = packbf(x2, x3); }
            }
            // layout repair: hfrag pair p' <- src quad ((q&1)*2+(p'>>1)), chunk q>>1, pair p'&1
            unsigned a00 = __shfl(P00, srcA, 64), a10 = __shfl(P10, srcA, 64);
            unsigned a01 = __shfl(P01, srcA, 64), a11 = __shfl(P11, srcA, 64);
            unsigned b00 = __shfl(P00, srcB, 64), b10 = __shfl(P10, srcB, 64);
            unsigned b01 = __shfl(P01, srcB, 64), b11 = __shfl(P11, srcB, 64);
            uint4 hu;
            hu.x = hiC ? a10 : a00;
            hu.y = hiC ? a11 : a01;
            hu.z = hiC ? b10 : b00;
            hu.w = hiC ? b11 : b01;
            s8v hfrag = __builtin_bit_cast(s8v, hu);
            acc = __builtin_amdgcn_mfma_f32_16x16x32_bf16(hfrag, w2F[kc*64 + l], acc, 0, 0, 0);
        }
#pragma unroll
        for (int reg = 0; reg < 4; ++reg) {
            float m = silu_f(acc[reg] + b2L[e15]);
            macc += m;
            int erow = hf*16 + q*4 + reg;
            mL[wid][erow][e15] = f2bs(m);
        }
    }

    // heads: 32x32x16 MFMA on m (B = mL^T via LDS round-trip)
    s8v mf = *(const s8v*)&mL[wid][l & 31][(l >> 5) * 8];
    f16v z16;
#pragma unroll
    for (int i = 0; i < 16; ++i) z16[i] = 0.f;

    float cwv, ccwv;
    {
        f16v C0 = __builtin_amdgcn_mfma_f32_32x32x16_bf16(cA0, mf, z16, 0, 0, 0);
        f16v C1 = __builtin_amdgcn_mfma_f32_32x32x16_bf16(cA1, mf, z16, 0, 0, 0);
        float val = 0.f;
#pragma unroll
        for (int reg = 0; reg < 16; ++reg) {
            int h = (reg & 3) + 8*(reg >> 2) + 4*(l >> 5);
            val += silu_f(C0[reg] + b1cL[h]) * cw2L[h];
            val += silu_f(C1[reg] + b1cL[h+32]) * cw2L[h+32];
        }
        val += __shfl_xor(val, 32, 64);
        cwv = val + coor_b2[0];
    }
    {
        f16v C0 = __builtin_amdgcn_mfma_f32_32x32x16_bf16(xA0, mf, z16, 0, 0, 0);
        f16v C1 = __builtin_amdgcn_mfma_f32_32x32x16_bf16(xA1, mf, z16, 0, 0, 0);
        float val = 0.f;
#pragma unroll
        for (int reg = 0; reg < 16; ++reg) {
            int h = (reg & 3) + 8*(reg >> 2) + 4*(l >> 5);
            val += silu_f(C0[reg] + b1xL[h]) * xw2L[h];
            val += silu_f(C1[reg] + b1xL[h+32]) * xw2L[h+32];
        }
        val += __shfl_xor(val, 32, 64);
        ccwv = val + cross_b2[0];
    }

    macc += __shfl_xor(macc, 16, 64);
    macc += __shfl_xor(macc, 32, 64);
    if (l < 16) ws_mi[(size_t)r*MD + l] = macc;

    float cxa = 0.f, cya = 0.f, cza = 0.f;
    if (l < 32) {
        size_t jb = (size_t)((b << 11) | jv) * 3;
        float cjx = coors[jb], cjy = coors[jb+1], cjz = coors[jb+2];
        float relx = cix - cjx, rely = ciy - cjy, relz = ciz - cjz;
        float cmjx = cjx - mx, cmjy = cjy - my, cmjz = cjz - mz;
        float crx = cmiy*cmjz - cmiz*cmjy;
        float cry = cmiz*cmjx - cmix*cmjz;
        float crz = cmix*cmjy - cmiy*cmjx;
        cxa = cwv*relx + ccwv*crx;
        cya = cwv*rely + ccwv*cry;
        cza = cwv*relz + ccwv*crz;
    }
#pragma unroll
    for (int mm = 1; mm < 64; mm <<= 1) {
        cxa += __shfl_xor(cxa, mm, 64);
        cya += __shfl_xor(cya, mm, 64);
        cza += __shfl_xor(cza, mm, 64);
    }
    if (l == 0) {
        out_coors[(size_t)r*3+0] = cix + cxa;
        out_coors[(size_t)r*3+1] = ciy + cya;
        out_coors[(size_t)r*3+2] = ciz + cza;
    }
}

// ---------------------------------------------------------------- launch
// ws layout (<= 11.6 MB):
//   [0,64)            ws_mean
//   [64, +1MB)        ws_idx
//   [1048640, +1MB)   ws_dist
//   [2097216, +512K)  ws_mi
//   [2621504, +8.9MB) ACall (4096 x 1088 bf16, per 2-batch chunk);
//                     hiddenB (8192x256 bf16, 4MB) overlays after edges done.
extern "C" void kernel_launch(void* const* d_in, const int* in_sizes, int n_in,
                              void* d_out, int out_size, void* d_ws, size_t ws_size,
                              hipStream_t stream) {
    const float* feats    = (const float*)d_in[0];
    const float* coors    = (const float*)d_in[1];
    const float* edge_w1  = (const float*)d_in[2];
    const float* edge_b1  = (const float*)d_in[3];
    const float* edge_w2  = (const float*)d_in[4];
    const float* edge_b2  = (const float*)d_in[5];
    const float* coor_w1  = (const float*)d_in[6];
    const float* coor_b1  = (const float*)d_in[7];
    const float* coor_w2  = (const float*)d_in[8];
    const float* coor_b2  = (const float*)d_in[9];
    const float* cross_w1 = (const float*)d_in[10];
    const float* cross_b1 = (const float*)d_in[11];
    const float* cross_w2 = (const float*)d_in[12];
    const float* cross_b2 = (const float*)d_in[13];
    const float* node_w1  = (const float*)d_in[14];
    const float* node_b1  = (const float*)d_in[15];
    const float* node_w2  = (const float*)d_in[16];
    const float* node_b2  = (const float*)d_in[17];

    char* ws = (char*)d_ws;
    float* ws_mean = (float*)ws;
    int*   ws_idx  = (int*)(ws + 64);
    float* ws_dist = (float*)(ws + 1048640);
    float* ws_mi   = (float*)(ws + 2097216);
    bf16*  ACall   = (bf16*)(ws + 2621504);
    bf16*  hiddenB = (bf16*)(ws + 2621504);   // overlays ACall (dead by node1)

    float* out_node  = (float*)d_out;
    float* out_coors = out_node + (size_t)NROWS * DD;

    topk_kernel<<<NROWS/4, 256, 0, stream>>>(coors, ws_idx, ws_dist, ws_mean);
    for (int c = 0; c < 2; ++c) {
        mfma_gemm_kernel<0><<<dim3(17, 64), 256, 0, stream>>>(
            feats + (size_t)c*RCHUNK*DD, nullptr, nullptr, edge_w1, edge_b1, nullptr,
            ACall, nullptr);
        edge_kernel<<<RCHUNK/4, 256, 0, stream>>>(
            c, coors, ACall, ws_idx, ws_dist, ws_mean,
            edge_w1, edge_w2, edge_b2,
            coor_w1, coor_b1, coor_w2, coor_b2,
            cross_w1, cross_b1, cross_w2, cross_b2,
            ws_mi, out_coors);
    }
    mfma_gemm_kernel<1><<<dim3(4, 128), 256, 0, stream>>>(
        feats, ws_mi, nullptr, node_w1, node_b1, nullptr, hiddenB, nullptr);
    mfma_gemm_kernel<2><<<dim3(2, 128), 256, 0, stream>>>(
        nullptr, nullptr, hiddenB, node_w2, node_b2, feats, nullptr, out_node);
}